// Round 8
// baseline (264.990 us; speedup 1.0000x reference)
//
#include <hip/hip_runtime.h>

#define HDIM 256
constexpr int N_SRC = 131072, N_MID = 32768, N_DST = 8192;
constexpr int E1 = 524288, E2 = 131072;
constexpr int N_PAIRS = 8192;

typedef __attribute__((ext_vector_type(8))) short bf16x8;
typedef __attribute__((ext_vector_type(4))) float f32x4;

__device__ __forceinline__ float bf2f(unsigned short u) {
    return __uint_as_float(((unsigned int)u) << 16);
}
__device__ __forceinline__ unsigned short f2bf(float f) {
    unsigned int x = __float_as_uint(f);
    x += 0x7fff + ((x >> 16) & 1);          // round-to-nearest-even
    return (unsigned short)(x >> 16);
}
__device__ __forceinline__ uint2 pack4(float v0, float v1, float v2, float v3) {
    uint2 r;
    r.x = (unsigned int)f2bf(v0) | ((unsigned int)f2bf(v1) << 16);
    r.y = (unsigned int)f2bf(v2) | ((unsigned int)f2bf(v3) << 16);
    return r;
}

// async global->LDS, 16B per lane; LDS dest = wave-uniform base + lane*16
__device__ __forceinline__ void gl16(const void* g, void* l)
{
    __builtin_amdgcn_global_load_lds(
        (const __attribute__((address_space(1))) unsigned int*)g,
        (__attribute__((address_space(3))) unsigned int*)l, 16, 0, 0);
}

// ---------------------------------------------------------------------------
// NOTE on MFMA operand order (this round's change): we call
//   acc = mfma(bfr, afr, acc)      (W-frag first, A-frag second)
// so D is indexed [w_col_group][a_row]: lane holds output row = l15 and
// 4 CONSECUTIVE output cols = (lane>>4)*4 + reg. Row-major stores are then
// one packed 8B uint2 per fragment instead of 4 scalar 2B stores.
// ---------------------------------------------------------------------------

// ---------------------------------------------------------------------------
// gemm_k (unfused, used for h2): C[M,256] = act([A0|A1] @ W^T + bias), bf16.
// Tile 64x256/block, BK=64, 8 waves, wave=32x64. global_load_lds staging with
// XOR-swizzled source + swizzled ds_read.
// ---------------------------------------------------------------------------
template<int KTOT, int ACT>
__global__ __launch_bounds__(512, 4)
void gemm_k(const void* __restrict__ A0v, const void* __restrict__ A1v,
            const unsigned short* __restrict__ Wb,
            const float* __restrict__ bias,
            unsigned short* __restrict__ C, int M)
{
    constexpr int KSTEPS = KTOT / 64;
    __shared__ unsigned short sW[256 * 64];                  // 32 KB
    __shared__ unsigned char  sA[8192];
    unsigned char* sWb = (unsigned char*)sW;

    const int t = threadIdx.x;
    const int w = t >> 6, lane = t & 63;
    const int l15 = lane & 15;
    const int wrow = w >> 2, wc = w & 3;
    const int bm = blockIdx.x * 64;
    const int rb = (lane >> 4) * 4;

    f32x4 acc[2][4];
#pragma unroll
    for (int m = 0; m < 2; ++m)
#pragma unroll
        for (int n = 0; n < 4; ++n) acc[m][n] = (f32x4){0.f, 0.f, 0.f, 0.f};

    for (int ks = 0; ks < KSTEPS; ++ks) {
        const int kw = ks * 64;
#pragma unroll
        for (int it = 0; it < 4; ++it) {
            const int slot = it * 512 + w * 64 + lane;
            const int row = slot >> 3, kc = slot & 7;
            const int kcs = kc ^ (row & 7);
            gl16(&Wb[(size_t)row * KTOT + kw + kcs * 8],
                 sWb + (it * 512 + w * 64) * 16);
        }
        {
            const unsigned short* A = (const unsigned short*)
                ((KTOT == 512 && ks >= 4) ? A1v : A0v);
            const int ka = (KTOT == 512) ? (ks & 3) * 64 : kw;
            const int slot = w * 64 + lane;
            const int row = slot >> 3, kc = slot & 7;
            const int kcs = kc ^ (row & 7);
            gl16(&A[(size_t)(bm + row) * 256 + ka + kcs * 8],
                 sA + (w * 64) * 16);
        }
        __syncthreads();

#pragma unroll
        for (int kk = 0; kk < 2; ++kk) {
            const int kc = kk * 4 + (lane >> 4);
            bf16x8 afr[2], bfr[4];
#pragma unroll
            for (int m = 0; m < 2; ++m) {
                const int row = wrow * 32 + m * 16 + l15;
                afr[m] = *(const bf16x8*)(sA +
                    (((row << 3) | (kc ^ (row & 7))) * 16));
            }
#pragma unroll
            for (int n = 0; n < 4; ++n) {
                const int r = wc * 64 + n * 16 + l15;
                bfr[n] = *(const bf16x8*)(sWb +
                    (((r << 3) | (kc ^ (r & 7))) * 16));
            }
#pragma unroll
            for (int m = 0; m < 2; ++m)
#pragma unroll
                for (int n = 0; n < 4; ++n)
                    acc[m][n] = __builtin_amdgcn_mfma_f32_16x16x32_bf16(
                        bfr[n], afr[m], acc[m][n], 0, 0, 0);
        }
        __syncthreads();
    }

    // packed epilogue: lane = row l15, 4 consecutive cols
#pragma unroll
    for (int n = 0; n < 4; ++n) {
        const int col0 = wc * 64 + n * 16 + rb;
        const float4 bv = *(const float4*)&bias[col0];
#pragma unroll
        for (int m = 0; m < 2; ++m) {
            const int row = bm + wrow * 32 + m * 16 + l15;
            float v0 = acc[m][n][0] + bv.x, v1 = acc[m][n][1] + bv.y;
            float v2 = acc[m][n][2] + bv.z, v3 = acc[m][n][3] + bv.w;
            if (ACT) { v0 = fmaxf(v0, 0.f); v1 = fmaxf(v1, 0.f);
                       v2 = fmaxf(v2, 0.f); v3 = fmaxf(v3, 0.f); }
            *(uint2*)&C[(size_t)row * 256 + col0] = pack4(v0, v1, v2, v3);
        }
    }
}

// ---------------------------------------------------------------------------
// FUSED double GEMM:
//   T  = act1( [A0|A1] @ W^T + bias1 )        (KTOT1 = 256 or 512)
//   C2 = act2( T @ Q^T + bias2 )              (K = 256)
// T tile kept in LDS (16B-chunk XOR swizzle); global C1 only rows < M1lim.
// FP32A: A reg-staged (2xfloat4 -> 8 f2bf -> 1 swizzled ds_write_b128), so
// conversion happens ONCE per element, not per fragment read.
// ---------------------------------------------------------------------------
template<int KTOT1, int FP32A, int ACT1, int ACT2>
__global__ __launch_bounds__(512, 4)
void gemm_fused(const void* __restrict__ A0v, const void* __restrict__ A1v,
                const unsigned short* __restrict__ Wb,   // [256][KTOT1]
                const float* __restrict__ bias1,
                unsigned short* __restrict__ C1, int M1lim,
                const unsigned short* __restrict__ Qb,   // [256][256]
                const float* __restrict__ bias2,
                unsigned short* __restrict__ C2, int M)
{
    constexpr int KSTEPS = KTOT1 / 64;
    __shared__ unsigned short sW[256 * 64];                  // 32 KB W/Q slices
    __shared__ unsigned char  sA[8192];                      // 8 KB A slice
    __shared__ unsigned short sHP[64 * 256];                 // 32 KB T tile
    unsigned char* sWb  = (unsigned char*)sW;
    unsigned char* sHPb = (unsigned char*)sHP;

    const int t = threadIdx.x;
    const int w = t >> 6, lane = t & 63;
    const int l15 = lane & 15;
    const int wrow = w >> 2, wc = w & 3;
    const int bm = blockIdx.x * 64;
    const int rb = (lane >> 4) * 4;

    f32x4 acc[2][4];
#pragma unroll
    for (int m = 0; m < 2; ++m)
#pragma unroll
        for (int n = 0; n < 4; ++n) acc[m][n] = (f32x4){0.f, 0.f, 0.f, 0.f};

    // ================= phase 1: first GEMM =================
    for (int ks = 0; ks < KSTEPS; ++ks) {
        const int kw = ks * 64;
#pragma unroll
        for (int it = 0; it < 4; ++it) {
            const int slot = it * 512 + w * 64 + lane;
            const int row = slot >> 3, kc = slot & 7;
            const int kcs = kc ^ (row & 7);
            gl16(&Wb[(size_t)row * KTOT1 + kw + kcs * 8],
                 sWb + (it * 512 + w * 64) * 16);
        }
        if constexpr (FP32A) {
            // reg-stage: 8 fp32 -> 8 bf16 -> one swizzled 16B ds_write
            const float* A = (const float*)A0v;
            const int arow = t >> 3, akc = t & 7;
            const float* ap = &A[(size_t)(bm + arow) * 256 + kw + akc * 8];
            const float4 u0 = *(const float4*)ap;
            const float4 u1 = *(const float4*)(ap + 4);
            uint4 pk;
            pk.x = (unsigned int)f2bf(u0.x) | ((unsigned int)f2bf(u0.y) << 16);
            pk.y = (unsigned int)f2bf(u0.z) | ((unsigned int)f2bf(u0.w) << 16);
            pk.z = (unsigned int)f2bf(u1.x) | ((unsigned int)f2bf(u1.y) << 16);
            pk.w = (unsigned int)f2bf(u1.z) | ((unsigned int)f2bf(u1.w) << 16);
            *(uint4*)(sA + ((arow << 3) | (akc ^ (arow & 7))) * 16) = pk;
        } else {
            const unsigned short* A = (const unsigned short*)
                ((KTOT1 == 512 && ks >= 4) ? A1v : A0v);
            const int ka = (KTOT1 == 512) ? (ks & 3) * 64 : kw;
            const int slot = w * 64 + lane;
            const int row = slot >> 3, kc = slot & 7;
            const int kcs = kc ^ (row & 7);
            gl16(&A[(size_t)(bm + row) * 256 + ka + kcs * 8],
                 sA + (w * 64) * 16);
        }
        __syncthreads();

#pragma unroll
        for (int kk = 0; kk < 2; ++kk) {
            const int kc = kk * 4 + (lane >> 4);
            bf16x8 afr[2], bfr[4];
#pragma unroll
            for (int m = 0; m < 2; ++m) {
                const int row = wrow * 32 + m * 16 + l15;
                afr[m] = *(const bf16x8*)(sA +
                    (((row << 3) | (kc ^ (row & 7))) * 16));
            }
#pragma unroll
            for (int n = 0; n < 4; ++n) {
                const int r = wc * 64 + n * 16 + l15;
                bfr[n] = *(const bf16x8*)(sWb +
                    (((r << 3) | (kc ^ (r & 7))) * 16));
            }
#pragma unroll
            for (int m = 0; m < 2; ++m)
#pragma unroll
                for (int n = 0; n < 4; ++n)
                    acc[m][n] = __builtin_amdgcn_mfma_f32_16x16x32_bf16(
                        bfr[n], afr[m], acc[m][n], 0, 0, 0);
        }
        __syncthreads();
    }

    // ====== phase 2: epilogue1 -> sHP (swizzled, 8B) + partial C1 (8B) ======
    const bool wr1 = (bm < M1lim);
#pragma unroll
    for (int n = 0; n < 4; ++n) {
        const int col0 = wc * 64 + n * 16 + rb;
        const float4 bv = *(const float4*)&bias1[col0];
#pragma unroll
        for (int m = 0; m < 2; ++m) {
            const int r = wrow * 32 + m * 16 + l15;   // block-local row
            float v0 = acc[m][n][0] + bv.x, v1 = acc[m][n][1] + bv.y;
            float v2 = acc[m][n][2] + bv.z, v3 = acc[m][n][3] + bv.w;
            if (ACT1) { v0 = fmaxf(v0, 0.f); v1 = fmaxf(v1, 0.f);
                        v2 = fmaxf(v2, 0.f); v3 = fmaxf(v3, 0.f); }
            const uint2 pk = pack4(v0, v1, v2, v3);
            *(uint2*)(sHPb + r * 512 + ((col0 >> 3) ^ (r & 7)) * 16
                      + (col0 & 4) * 2) = pk;
            if (wr1) *(uint2*)&C1[(size_t)(bm + r) * 256 + col0] = pk;
        }
    }
    __syncthreads();

    // ================= phase 3: second GEMM (T @ Q^T) =================
#pragma unroll
    for (int m = 0; m < 2; ++m)
#pragma unroll
        for (int n = 0; n < 4; ++n) acc[m][n] = (f32x4){0.f, 0.f, 0.f, 0.f};

    for (int ks2 = 0; ks2 < 4; ++ks2) {
#pragma unroll
        for (int it = 0; it < 4; ++it) {
            const int slot = it * 512 + w * 64 + lane;
            const int row = slot >> 3, kc = slot & 7;
            const int kcs = kc ^ (row & 7);
            gl16(&Qb[(size_t)row * 256 + ks2 * 64 + kcs * 8],
                 sWb + (it * 512 + w * 64) * 16);
        }
        __syncthreads();
#pragma unroll
        for (int kk = 0; kk < 2; ++kk) {
            const int kc = kk * 4 + (lane >> 4);
            bf16x8 afr[2], bfr[4];
#pragma unroll
            for (int m = 0; m < 2; ++m) {
                const int r = wrow * 32 + m * 16 + l15;
                const int cch = ks2 * 8 + kc;
                afr[m] = *(const bf16x8*)(sHPb + r * 512 + (cch ^ (r & 7)) * 16);
            }
#pragma unroll
            for (int n = 0; n < 4; ++n) {
                const int r = wc * 64 + n * 16 + l15;
                bfr[n] = *(const bf16x8*)(sWb +
                    (((r << 3) | (kc ^ (r & 7))) * 16));
            }
#pragma unroll
            for (int m = 0; m < 2; ++m)
#pragma unroll
                for (int n = 0; n < 4; ++n)
                    acc[m][n] = __builtin_amdgcn_mfma_f32_16x16x32_bf16(
                        bfr[n], afr[m], acc[m][n], 0, 0, 0);
        }
        __syncthreads();
    }

    // ================= phase 4: epilogue2 -> C2 (packed 8B) =================
#pragma unroll
    for (int n = 0; n < 4; ++n) {
        const int col0 = wc * 64 + n * 16 + rb;
        const float4 bv = *(const float4*)&bias2[col0];
#pragma unroll
        for (int m = 0; m < 2; ++m) {
            const int row = bm + wrow * 32 + m * 16 + l15;
            float v0 = acc[m][n][0] + bv.x, v1 = acc[m][n][1] + bv.y;
            float v2 = acc[m][n][2] + bv.z, v3 = acc[m][n][3] + bv.w;
            if (ACT2) { v0 = fmaxf(v0, 0.f); v1 = fmaxf(v1, 0.f);
                        v2 = fmaxf(v2, 0.f); v3 = fmaxf(v3, 0.f); }
            *(uint2*)&C2[(size_t)row * 256 + col0] = pack4(v0, v1, v2, v3);
        }
    }
}

// ---------------------------------------------------------------------------
// Convert the 5 weight matrices fp32 -> bf16
// ---------------------------------------------------------------------------
__global__ __launch_bounds__(256)
void conv_w(const float* __restrict__ Wp, const float* __restrict__ Q1,
            const float* __restrict__ W1, const float* __restrict__ Q2,
            const float* __restrict__ W2, unsigned short* __restrict__ out)
{
    const int i = blockIdx.x * 256 + threadIdx.x;
    const float* src; int off;
    if (i < 65536)       { src = Wp; off = i; }
    else if (i < 131072) { src = Q1; off = i - 65536; }
    else if (i < 262144) { src = W1; off = i - 131072; }
    else if (i < 327680) { src = Q2; off = i - 262144; }
    else                 { src = W2; off = i - 327680; }
    out[i] = f2bf(src[off]);
}

// ---------------------------------------------------------------------------
// CSR build (both graphs fused): count -> scan -> fill
// ---------------------------------------------------------------------------
__global__ void edge_count2(const int* __restrict__ dst1, const int* __restrict__ dst2,
                            int* __restrict__ counts1, int* __restrict__ counts2)
{
    const int i = blockIdx.x * blockDim.x + threadIdx.x;
    if (i < E1) atomicAdd(&counts1[dst1[i]], 1);
    else        atomicAdd(&counts2[dst2[i - E1]], 1);
}

// Coalesced single-block scan (LDS-staged). N = 1024*PER.
template<int PER>
__global__ __launch_bounds__(1024)
void scan_kernel(const int* __restrict__ counts,
                 int* __restrict__ row_start, int* __restrict__ cursor)
{
    constexpr int N = 1024 * PER;
    __shared__ int lds[1024][PER + 1];
    __shared__ int part[1024];
    const int t = threadIdx.x;
    for (int i = t; i < N; i += 1024) lds[i / PER][i % PER] = counts[i];
    __syncthreads();
    int s = 0;
#pragma unroll
    for (int j = 0; j < PER; ++j) s += lds[t][j];
    part[t] = s;
    __syncthreads();
    for (int off = 1; off < 1024; off <<= 1) {
        int v = (t >= off) ? part[t - off] : 0;
        __syncthreads();
        part[t] += v;
        __syncthreads();
    }
    int run = (t == 0) ? 0 : part[t - 1];
#pragma unroll
    for (int j = 0; j < PER; ++j) {
        const int c = lds[t][j];
        lds[t][j] = run;
        run += c;
    }
    __syncthreads();
    for (int i = t; i < N; i += 1024) {
        const int v = lds[i / PER][i % PER];
        row_start[i] = v;
        cursor[i] = v;
    }
    if (t == 1023) row_start[N] = run;
}

__global__ void edge_fill2(const int* __restrict__ dst1, const int* __restrict__ src1,
                           const float* __restrict__ w1,
                           const int* __restrict__ dst2, const int* __restrict__ src2,
                           const float* __restrict__ w2,
                           int* __restrict__ cur1, int* __restrict__ cur2,
                           int* __restrict__ ssrc1, float* __restrict__ sw1,
                           int* __restrict__ ssrc2, float* __restrict__ sw2)
{
    const int i = blockIdx.x * blockDim.x + threadIdx.x;
    if (i < E1) {
        const int p = atomicAdd(&cur1[dst1[i]], 1);
        ssrc1[p] = src1[i];
        sw1[p]   = w1[i];
    } else {
        const int j = i - E1;
        const int p = atomicAdd(&cur2[dst2[j]], 1);
        ssrc2[p] = src2[j];
        sw2[p]   = w2[j];
    }
}

// ---------------------------------------------------------------------------
// Weighted aggregate with 4x memory-level parallelism (one wave per dst row).
// ---------------------------------------------------------------------------
__global__ __launch_bounds__(256)
void aggregate(const unsigned short* __restrict__ nsrc,
               const int* __restrict__ ssrc, const float* __restrict__ sw,
               const int* __restrict__ rs, unsigned short* __restrict__ agg)
{
    const int d = blockIdx.x * 4 + (threadIdx.x >> 6);
    const int lane = threadIdx.x & 63;
    const int p0 = rs[d], p1 = rs[d + 1];
    float a0 = 0.f, a1 = 0.f, a2 = 0.f, a3 = 0.f, wacc = 0.f;

    for (int base = p0; base < p1; base += 64) {
        const int cnt = min(64, p1 - base);
        int   mySrc = 0;
        float myW   = 0.f;
        if (lane < cnt) { mySrc = ssrc[base + lane]; myW = sw[base + lane]; }
        wacc += myW;
        int j = 0;
        for (; j + 4 <= cnt; j += 4) {
            const int   s0 = __shfl(mySrc, j + 0), s1 = __shfl(mySrc, j + 1);
            const int   s2 = __shfl(mySrc, j + 2), s3 = __shfl(mySrc, j + 3);
            const float w0 = __shfl(myW, j + 0),   w1 = __shfl(myW, j + 1);
            const float w2 = __shfl(myW, j + 2),   w3 = __shfl(myW, j + 3);
            const ushort4 r0 = *reinterpret_cast<const ushort4*>(&nsrc[(size_t)s0 * 256 + lane * 4]);
            const ushort4 r1 = *reinterpret_cast<const ushort4*>(&nsrc[(size_t)s1 * 256 + lane * 4]);
            const ushort4 r2 = *reinterpret_cast<const ushort4*>(&nsrc[(size_t)s2 * 256 + lane * 4]);
            const ushort4 r3 = *reinterpret_cast<const ushort4*>(&nsrc[(size_t)s3 * 256 + lane * 4]);
            a0 += bf2f(r0.x) * w0; a1 += bf2f(r0.y) * w0; a2 += bf2f(r0.z) * w0; a3 += bf2f(r0.w) * w0;
            a0 += bf2f(r1.x) * w1; a1 += bf2f(r1.y) * w1; a2 += bf2f(r1.z) * w1; a3 += bf2f(r1.w) * w1;
            a0 += bf2f(r2.x) * w2; a1 += bf2f(r2.y) * w2; a2 += bf2f(r2.z) * w2; a3 += bf2f(r2.w) * w2;
            a0 += bf2f(r3.x) * w3; a1 += bf2f(r3.y) * w3; a2 += bf2f(r3.z) * w3; a3 += bf2f(r3.w) * w3;
        }
        for (; j < cnt; ++j) {
            const int   s = __shfl(mySrc, j);
            const float wj = __shfl(myW, j);
            const ushort4 r = *reinterpret_cast<const ushort4*>(&nsrc[(size_t)s * 256 + lane * 4]);
            a0 += bf2f(r.x) * wj; a1 += bf2f(r.y) * wj; a2 += bf2f(r.z) * wj; a3 += bf2f(r.w) * wj;
        }
    }
    float ws = wacc;
#pragma unroll
    for (int off = 32; off > 0; off >>= 1) ws += __shfl_xor(ws, off);
    const float inv = 1.f / fmaxf(ws, 1.f);
    ushort4 o;
    o.x = f2bf(a0 * inv); o.y = f2bf(a1 * inv);
    o.z = f2bf(a2 * inv); o.w = f2bf(a3 * inv);
    *reinterpret_cast<ushort4*>(&agg[(size_t)d * 256 + lane * 4]) = o;
}

// ---------------------------------------------------------------------------
// z = normalize(hp[:N_DST] + h2)   (bf16 in, fp32 out)
// ---------------------------------------------------------------------------
__global__ __launch_bounds__(256)
void skip_norm(const unsigned short* __restrict__ hp, const unsigned short* __restrict__ h2,
               float* __restrict__ z)
{
    __shared__ float sm[4];
    const int d = blockIdx.x, t = threadIdx.x;
    const float v = bf2f(hp[(size_t)d * 256 + t]) + bf2f(h2[(size_t)d * 256 + t]);
    float s = v * v;
#pragma unroll
    for (int off = 32; off > 0; off >>= 1) s += __shfl_down(s, off);
    if ((t & 63) == 0) sm[t >> 6] = s;
    __syncthreads();
    const float tot = sm[0] + sm[1] + sm[2] + sm[3];
    const float nrm = sqrtf(tot);
    const float inv = (nrm == 0.f) ? 1.f : 1.f / nrm;
    z[(size_t)d * 256 + t] = v * inv;
}

// ---------------------------------------------------------------------------
__global__ __launch_bounds__(256)
void score_kernel(const float* __restrict__ z, const float* __restrict__ bias,
                  const int* __restrict__ nids,
                  const int* __restrict__ ps, const int* __restrict__ pd,
                  const int* __restrict__ ns, const int* __restrict__ nd,
                  float* __restrict__ out)
{
    __shared__ float sm[8];
    const int p = blockIdx.x, t = threadIdx.x;
    const int a = ps[p], b = pd[p], c = ns[p], d2 = nd[p];
    float vp = z[(size_t)a * 256 + t] * z[(size_t)b * 256 + t];
    float vn = z[(size_t)c * 256 + t] * z[(size_t)d2 * 256 + t];
#pragma unroll
    for (int off = 32; off > 0; off >>= 1) {
        vp += __shfl_down(vp, off);
        vn += __shfl_down(vn, off);
    }
    if ((t & 63) == 0) { sm[t >> 6] = vp; sm[4 + (t >> 6)] = vn; }
    __syncthreads();
    if (t == 0) {
        const float pos = sm[0] + sm[1] + sm[2] + sm[3] + bias[nids[a]] + bias[nids[b]];
        const float neg = sm[4] + sm[5] + sm[6] + sm[7] + bias[nids[c]] + bias[nids[d2]];
        out[p] = fmaxf(neg - pos + 1.0f, 0.f);
    }
}

// ---------------------------------------------------------------------------
extern "C" void kernel_launch(void* const* d_in, const int* in_sizes, int n_in,
                              void* d_out, int out_size, void* d_ws, size_t ws_size,
                              hipStream_t stream)
{
    const float* feat = (const float*)d_in[0];
    const float* Wp   = (const float*)d_in[1];
    const float* bp   = (const float*)d_in[2];
    const float* Q1   = (const float*)d_in[3];
    const float* bq1  = (const float*)d_in[4];
    const float* W1   = (const float*)d_in[5];
    const float* bw1  = (const float*)d_in[6];
    const float* Q2   = (const float*)d_in[7];
    const float* bq2  = (const float*)d_in[8];
    const float* W2   = (const float*)d_in[9];
    const float* bw2  = (const float*)d_in[10];
    const float* w1   = (const float*)d_in[11];
    const float* w2   = (const float*)d_in[12];
    const float* bias = (const float*)d_in[13];
    const int* src1   = (const int*)d_in[14];
    const int* dst1   = (const int*)d_in[15];
    const int* src2   = (const int*)d_in[16];
    const int* dst2   = (const int*)d_in[17];
    const int* pos_src = (const int*)d_in[18];
    const int* pos_dst = (const int*)d_in[19];
    const int* neg_src = (const int*)d_in[20];
    const int* neg_dst = (const int*)d_in[21];
    const int* nids    = (const int*)d_in[22];

    // workspace layout
    unsigned short* hp   = (unsigned short*)d_ws;              // [N_SRC,256] (only :N_MID written)
    unsigned short* n1   = hp   + (size_t)N_SRC * 256;         // [N_SRC,256] (reused as n2)
    unsigned short* aggb = n1   + (size_t)N_SRC * 256;         // [N_MID,256] (reused as agg2)
    unsigned short* h1   = aggb + (size_t)N_MID * 256;         // [N_MID,256] (only :N_DST written)
    unsigned short* h2   = h1   + (size_t)N_MID * 256;         // [N_DST,256]
    unsigned short* wb   = h2   + (size_t)N_DST * 256;         // 458752 bf16 weights
    float* zb            = (float*)(wb + 458752);              // [N_DST,256] fp32
    int* counts1 = (int*)(zb + (size_t)N_DST * 256);
    int* counts2 = counts1 + N_MID;                            // adjacent -> one memset
    int* rs1     = counts2 + N_DST;
    int* cur1    = rs1 + N_MID + 1;
    int* ssrc1   = cur1 + N_MID;
    float* sw1   = (float*)(ssrc1 + E1);
    int* rs2     = (int*)(sw1 + E1);
    int* cur2    = rs2 + N_DST + 1;
    int* ssrc2   = cur2 + N_DST;
    float* sw2   = (float*)(ssrc2 + E2);

    const unsigned short* Wpb = wb;
    const unsigned short* Q1b = wb + 65536;
    const unsigned short* W1b = wb + 131072;
    const unsigned short* Q2b = wb + 262144;
    const unsigned short* W2b = wb + 327680;

    hipMemsetAsync(counts1, 0, (N_MID + N_DST) * sizeof(int), stream);

    const dim3 blk(256);
    conv_w<<<1792, blk, 0, stream>>>(Wp, Q1, W1, Q2, W2, wb);

    // hp = feat @ Wp^T + bp (rows<N_MID to global); n1 = relu(hp @ Q1^T + bq1)
    gemm_fused<256, 1, 0, 1><<<N_SRC / 64, 512, 0, stream>>>(
        feat, nullptr, Wpb, bp, hp, N_MID, Q1b, bq1, n1, N_SRC);

    // CSR build (both graphs)
    edge_count2<<<(E1 + E2) / 256, blk, 0, stream>>>(dst1, dst2, counts1, counts2);
    scan_kernel<32><<<1, 1024, 0, stream>>>(counts1, rs1, cur1);
    scan_kernel<8><<<1, 1024, 0, stream>>>(counts2, rs2, cur2);
    edge_fill2<<<(E1 + E2) / 256, blk, 0, stream>>>(dst1, src1, w1, dst2, src2, w2,
                                                    cur1, cur2, ssrc1, sw1, ssrc2, sw2);

    // conv1 aggregation
    aggregate<<<N_MID / 4, blk, 0, stream>>>(n1, ssrc1, sw1, rs1, aggb);

    // h1 = relu([agg1|hp]@W1^T + bw1) (rows<N_DST); n2 = relu(h1 @ Q2^T + bq2)
    gemm_fused<512, 0, 1, 1><<<N_MID / 64, 512, 0, stream>>>(
        aggb, hp, W1b, bw1, h1, N_DST, Q2b, bq2, n1, N_MID);

    // conv2 aggregation
    aggregate<<<N_DST / 4, blk, 0, stream>>>(n1, ssrc2, sw2, rs2, aggb);

    // h2 = relu( [agg2 | h1[:N_DST]] @ W2^T + bw2 )
    gemm_k<512, 1><<<N_DST / 64, 512, 0, stream>>>(
        aggb, h1, W2b, bw2, h2, N_DST);

    // z = normalize(hp[:N_DST] + h2); scores
    skip_norm<<<N_DST, blk, 0, stream>>>(hp, h2, zb);
    score_kernel<<<N_PAIRS, blk, 0, stream>>>(zb, bias, nids,
                                              pos_src, pos_dst, neg_src, neg_dst,
                                              (float*)d_out);
}